// Round 1
// baseline (555.717 us; speedup 1.0000x reference)
//
#include <hip/hip_runtime.h>
#include <hip/hip_cooperative_groups.h>
#include <math.h>

namespace cg = cooperative_groups;

// Problem constants
#define GG 16
#define NNODE 512
#define EEDGE 2048
#define KEEPN 256
#define PITERS 64
#define NNT 8192    // G*N
#define NET 32768   // G*E

typedef float vfloat4 __attribute__((ext_vector_type(4)));

// workspace float offsets (unchanged layout)
#define WS_C1N 0
#define WS_C2N 8192
#define WS_BN  16384
#define WS_C1E 24576
#define WS_C2E 57344
#define WS_BE  90112
#define WS_SNW 122880   // node score * mask (8192)
#define WS_SEW 131072   // edge score * keep (32768)
#define WS_KLIST 163840 // int[32768]
#define WS_KCNT 196608  // int[16]
#define WS_SCALE 196624 // float[16]

// output float offsets: xn | L0 | xe | L1
#define O_XN 0
#define O_L0 524288
#define O_XE 4718592
#define O_L1 6815744

// zero-space: float4 indices over concatenated L0 (4,194,304 f) || L1 (67,108,864 f)
#define L04 1048576      // float4 count of L0
#define ZTOT4 17825792   // total float4 to zero (272 MiB)

#define NBLK 256
#define NTHR 512
#define ZBLK (NBLK - 16)   // 240 zeroing blocks in phase 2

// LDS arena (phase-aliased), 37 KB
#define SM_AUG 0        // 512 f
#define SM_SNW 512      // 512 f, later reused as offS (int)
#define SM_RED 1024     // 8 f
#define SM_IWS 1032     // 8 int
#define SM_KCP 1040     // 1 int
#define SM_S0  1056     // 8200-float scratch
#define SM_TOT 9256
#define DCAP 12

// ---------------------------------------------------------------------------
// Single cooperative kernel:
//  Phase 1 (all blocks): per-row channel dots -> ws (c1/c2/bs for nodes+edges)
//  Phase 2: blocks 0..15 per-graph pipeline (verbatim from k_pool);
//           blocks 16..255 zero ALL of L0+L1 (272 MiB, nontemporal)
//  Phase 3 (all blocks): dense xn/xe scaling + L0 scatter + L1 pair enumeration
__global__ __launch_bounds__(NTHR) void k_fused(
    const float* __restrict__ xn, const float* __restrict__ xe,
    const float* __restrict__ Wn, const float* __restrict__ We,
    const int* __restrict__ src_n, const int* __restrict__ dst_n, const float* __restrict__ wn,
    const int* __restrict__ src_e, const int* __restrict__ dst_e, const float* __restrict__ we,
    const int* __restrict__ edge_u, const int* __restrict__ edge_v,
    const float* __restrict__ bnp, const float* __restrict__ bep,
    float* __restrict__ ws, float* __restrict__ out) {
  const int tid = threadIdx.x;
  const int bid = blockIdx.x;
  __shared__ float smem[SM_TOT];
  cg::grid_group grid = cg::this_grid();

  // ================= Phase 1: channel dots (all blocks) =================
  {
    const int lane = tid & 63;
    const int gwave = (bid * NTHR + tid) >> 6;   // 0..2047
    #pragma unroll 2
    for (int n = 0; n < 20; ++n) {
      int gw = gwave + n * 2048;                 // 0..40959
      const float* x; const float* W; int row; float *c1, *c2, *bs;
      if (gw < NNT) {
        row = gw; x = xn + (size_t)row * 64; W = Wn;
        c1 = ws + WS_C1N; c2 = ws + WS_C2N; bs = ws + WS_BN;
      } else {
        row = gw - NNT;
        x = xe + (size_t)row * 64; W = We;
        c1 = ws + WS_C1E; c2 = ws + WS_C2E; bs = ws + WS_BE;
      }
      float v = x[lane];
      float r0 = v * W[lane];
      float r1 = v * W[64 + lane];
      float r2 = v * W[128 + lane];
      for (int o = 32; o; o >>= 1) {
        r0 += __shfl_xor(r0, o, 64);
        r1 += __shfl_xor(r1, o, 64);
        r2 += __shfl_xor(r2, o, 64);
      }
      if (lane == 0) { c1[row] = r1; c2[row] = r2; bs[row] = r0 + r1 + r2; }
    }
  }
  grid.sync();

  // ================= Phase 2: pipeline (0..15) || zero L0+L1 (16..) =====
  if (bid >= 16) {
    vfloat4 z = (vfloat4)(0.f);
    vfloat4* o4 = (vfloat4*)out;
    for (int i = (bid - 16) * NTHR + tid; i < ZTOT4; i += ZBLK * NTHR) {
      int f = (i < L04) ? (O_L0 / 4 + i) : (O_L1 / 4 + (i - L04));
      __builtin_nontemporal_store(z, &o4[f]);
    }
  } else {
    int* smi = (int*)smem;
    float* aug = smem + SM_AUG;
    float* snw = smem + SM_SNW;
    float* red = smem + SM_RED;
    int*   iws = smi + SM_IWS;
    int*   kcp = smi + SM_KCP;

    const int g = bid;
    const int roffN = g * NNODE;
    const int roffE = g * EEDGE;
    const int lane = tid & 63, wid = tid >> 6;
    float biasN = bnp[0], biasE = bep[0];

    // ---- node message passing (scratch: 5 x 512 at S0) ----
    {
      float* c1n = smem + SM_S0;
      float* c2n = smem + SM_S0 + 512;
      float* d1n = smem + SM_S0 + 1024;
      float* d2n = smem + SM_S0 + 1536;
      float* e2n = smem + SM_S0 + 2048;
      c1n[tid] = ws[WS_C1N + roffN + tid];
      c2n[tid] = ws[WS_C2N + roffN + tid];
      d1n[tid] = 0.f; d2n[tid] = 0.f; e2n[tid] = 0.f;
      __syncthreads();
      for (int t = tid; t < 4096; t += 512) {
        int idx = (t < 2048) ? (g * 2048 + t) : (32768 + g * 2048 + (t - 2048));
        int s = src_n[idx] - roffN, d = dst_n[idx] - roffN;
        float w = wn[idx];
        atomicAdd(&d1n[d], w * c1n[s]);
        atomicAdd(&d2n[d], w * c2n[s]);
      }
      __syncthreads();
      for (int t = tid; t < 4096; t += 512) {
        int idx = (t < 2048) ? (g * 2048 + t) : (32768 + g * 2048 + (t - 2048));
        int s = src_n[idx] - roffN, d = dst_n[idx] - roffN;
        atomicAdd(&e2n[d], wn[idx] * d2n[s]);
      }
      __syncthreads();
      float t = ws[WS_BN + roffN + tid] - d1n[tid] - 2.0f * d2n[tid]
              + 0.5f * e2n[tid] + biasN;
      float s = 1.0f / (1.0f + expf(-t));
      snw[tid] = s; aug[tid] = s;
      __syncthreads();
    }

    // ---- edge message passing ----
    float* seS = smem + SM_S0 + 2048;   // survives into pool phase (old c2e)
    int*   suv = smi + SM_S0;           // packed u|v<<16 (old c1e/e2e, written last)
    {
      float* c1e = smem + SM_S0;
      float* c2e = smem + SM_S0 + 2048;
      float* d1e = smem + SM_S0 + 4096;
      float* d2e = smem + SM_S0 + 6144;
      float* e2e = smem + SM_S0;        // aliases c1e after hop 1
      for (int i = tid; i < EEDGE; i += 512) {
        c1e[i] = ws[WS_C1E + roffE + i];
        c2e[i] = ws[WS_C2E + roffE + i];
        d1e[i] = 0.f; d2e[i] = 0.f;
      }
      __syncthreads();
      for (int t = tid; t < 8192; t += 512) {
        int idx = g * 8192 + t;
        int s = src_e[idx] - roffE, d = dst_e[idx] - roffE;
        float w = we[idx];
        atomicAdd(&d1e[d], w * c1e[s]);
        atomicAdd(&d2e[d], w * c2e[s]);
      }
      __syncthreads();
      for (int i = tid; i < EEDGE; i += 512) e2e[i] = 0.f;
      __syncthreads();
      for (int t = tid; t < 8192; t += 512) {
        int idx = g * 8192 + t;
        int s = src_e[idx] - roffE, d = dst_e[idx] - roffE;
        atomicAdd(&e2e[d], we[idx] * d2e[s]);
      }
      __syncthreads();
      for (int e = tid; e < EEDGE; e += 512) {
        float t = ws[WS_BE + roffE + e] - d1e[e] - 2.0f * d2e[e]
                + 0.5f * e2e[e] + biasE;
        float s = 1.0f / (1.0f + expf(-t));
        int u = edge_u[roffE + e], v = edge_v[roffE + e];
        seS[e] = s;                       // seS == c2e slot e (c2 dead)
        suv[e] = u | (v << 16);           // suv == e2e slot e (read before write)
        atomicAdd(&aug[u], s);
        atomicAdd(&aug[v], s);
      }
      __syncthreads();
    }

    // ---- pool-phase scratch ----
    unsigned short* adjU = (unsigned short*)(smem + SM_S0 + 4096); // 4096 ushorts
    float* wvA = smem + SM_S0 + 6144;   // 513 (+pad)
    float* wvB = smem + SM_S0 + 6660;   // 513 (+pad)
    int* maskS = smi + SM_S0 + 7176;
    int* degS  = smi + SM_S0 + 7688;
    int* offS  = smi + SM_SNW;          // reuses snw after SNW written out

    // ---- rank-based top-256 (exact stable argsort(-aug)[:256]) ----
    {
      float a = aug[tid];
      int r = 0;
      #pragma unroll 8
      for (int j = 0; j < NNODE; ++j) {
        float b = aug[j];
        r += (b > a) || (b == a && j < tid);
      }
      maskS[tid] = (r < KEEPN) ? 1 : 0;
      degS[tid] = 0;
    }
    if (tid == 0) *kcp = 0;
    __syncthreads();
    ws[WS_SNW + roffN + tid] = snw[tid] * (float)maskS[tid];

    // ---- keep_e, klist compaction, degree count ----
    int* wsi = (int*)ws;
    for (int e = tid; e < EEDGE; e += 512) {
      int p2 = suv[e];
      int u = p2 & 0xffff, v = p2 >> 16;
      int k = maskS[u] & maskS[v];
      ws[WS_SEW + roffE + e] = seS[e] * (float)k;
      if (k) {
        int p = atomicAdd(kcp, 1);
        wsi[WS_KLIST + roffE + p] = e;
        atomicAdd(&degS[u], 1);
        atomicAdd(&degS[v], 1);
      }
    }
    __syncthreads();
    if (tid == 0) wsi[WS_KCNT + g] = *kcp;

    // ---- exclusive prefix of deg via wave scan ----
    int dv = degS[tid];
    int inc = dv;
    for (int o = 1; o < 64; o <<= 1) {
      int t = __shfl_up(inc, o, 64);
      if (lane >= o) inc += t;
    }
    if (lane == 63) iws[wid] = inc;
    __syncthreads();
    int base = 0;
    for (int k = 0; k < wid; ++k) base += iws[k];
    int myStart = base + inc - dv;
    offS[tid] = myStart;
    __syncthreads();

    // ---- CSR fill (ushort adjacency) ----
    for (int e = tid; e < EEDGE; e += 512) {
      int p2 = suv[e];
      int u = p2 & 0xffff, v = p2 >> 16;
      if (maskS[u] & maskS[v]) {
        int pu = atomicAdd(&offS[u], 1); adjU[pu] = (unsigned short)v;
        int pv = atomicAdd(&offS[v], 1); adjU[pv] = (unsigned short)u;
      }
    }
    __syncthreads();
    int myDeg = dv;
    int myEnd = myStart + myDeg;

    // ---- register-cached adjacency (pad -> pinned zero cell 512) ----
    int nbr[DCAP];
    #pragma unroll
    for (int k = 0; k < DCAP; ++k)
      nbr[k] = (k < myDeg) ? (int)adjU[myStart + k] : NNODE;
    bool ovf = myDeg > DCAP;

    wvA[tid] = 0.04419417382415922f; // 1/sqrt(512)
    if (tid == 0) { wvA[NNODE] = 0.f; wvB[NNODE] = 0.f; }
    __syncthreads();
    float* wcur = wvA; float* wnext = wvB;
    for (int it = 0; it < PITERS; ++it) {
      float acc = (float)myDeg * wcur[tid];
      #pragma unroll
      for (int k = 0; k < DCAP; ++k) acc -= wcur[nbr[k]];
      if (ovf) for (int p = myStart + DCAP; p < myEnd; ++p) acc -= wcur[(int)adjU[p]];
      if ((it & 7) == 7) {
        float sq = acc * acc;
        for (int o = 32; o; o >>= 1) sq += __shfl_xor(sq, o, 64);
        if (lane == 0) red[wid] = sq;
        __syncthreads();
        float tot = red[0] + red[1] + red[2] + red[3]
                  + red[4] + red[5] + red[6] + red[7];
        wnext[tid] = acc * (1.0f / (sqrtf(tot) + 1e-12f));
      } else {
        wnext[tid] = acc;
      }
      __syncthreads();
      float* tmp = wcur; wcur = wnext; wnext = tmp;
    }
    // ---- Rayleigh quotient (iter 63 normalized) ----
    {
      float wv_ = wcur[tid];
      float acc = (float)myDeg * wv_;
      #pragma unroll
      for (int k = 0; k < DCAP; ++k) acc -= wcur[nbr[k]];
      if (ovf) for (int p = myStart + DCAP; p < myEnd; ++p) acc -= wcur[(int)adjU[p]];
      float pr = wv_ * acc;
      for (int o = 32; o; o >>= 1) pr += __shfl_xor(pr, o, 64);
      if (lane == 0) red[wid] = pr;
      __syncthreads();
      if (tid == 0) {
        float lam = red[0] + red[1] + red[2] + red[3]
                  + red[4] + red[5] + red[6] + red[7];
        ws[WS_SCALE + g] = 2.0f / (lam + 1e-12f);
      }
    }
  }
  grid.sync();

  // ================= Phase 3: outputs (all blocks) ======================
  const int* wsi2 = (const int*)ws;
  // dense xn (131072 f4) then xe (524288 f4): 5 x 131072 grid-stride exact
  {
    int u = bid * NTHR + tid;
    #pragma unroll
    for (int k = 0; k < 5; ++k) {
      if (u < 131072) {
        int row = u >> 4;
        float s = ws[WS_SNW + row];
        float4 x4 = ((const float4*)xn)[u];
        ((float4*)(out + O_XN))[u] = make_float4(x4.x * s, x4.y * s, x4.z * s, x4.w * s);
      } else {
        int idx = u - 131072;
        int row = idx >> 4;
        float s = ws[WS_SEW + row];
        float4 x4 = ((const float4*)xe)[idx];
        ((float4*)(out + O_XE))[idx] = make_float4(x4.x * s, x4.y * s, x4.z * s, x4.w * s);
      }
      u += NBLK * NTHR;
    }
  }
  // L0 scatter: blocks 16..31, one graph each
  if (bid >= 16 && bid < 32) {
    int g = bid - 16;
    int cnt = wsi2[WS_KCNT + g];
    float s = ws[WS_SCALE + g];
    float* L0 = out + O_L0 + (long long)g * (NNODE * NNODE);
    const int* kl = wsi2 + WS_KLIST + g * EEDGE;
    const int* eu = edge_u + g * EEDGE;
    const int* ev = edge_v + g * EEDGE;
    for (int t = tid; t < cnt; t += NTHR) {
      int e = kl[t];
      int u = eu[e], v = ev[e];
      atomicAdd(&L0[u * NNODE + u], s);
      atomicAdd(&L0[v * NNODE + v], s);
      atomicAdd(&L0[u * NNODE + v], -s);
      atomicAdd(&L0[v * NNODE + u], -s);
    }
  }
  // L1 pair enumeration: 4096 virtual units = 256 blocks x 16
  for (int it = 0; it < 16; ++it) {
    int q = bid * 16 + it;            // 0..4095
    int g = q >> 8, sb = q & 255;
    int cnt = wsi2[WS_KCNT + g];
    float s = ws[WS_SCALE + g];
    float* L1 = out + O_L1 + (long long)g * (EEDGE * EEDGE);
    const int* kl = wsi2 + WS_KLIST + g * EEDGE;
    const int* eu = edge_u + g * EEDGE;
    const int* ev = edge_v + g * EEDGE;
    for (int a = sb; a < cnt; a += 256) {
      int e1 = kl[a];
      int u1 = eu[e1], v1 = ev[e1];
      long long rowoff = (long long)e1 * EEDGE;
      for (int b2 = tid; b2 < cnt; b2 += NTHR) {
        int e2 = kl[b2];
        int u2 = eu[e2], v2 = ev[e2];
        int val = (u1 == u2) + (v1 == v2) - (v1 == u2) - (u1 == v2);
        if (val) L1[rowoff + e2] = s * (float)val;
      }
    }
  }
}

// ---------------------------------------------------------------------------
extern "C" void kernel_launch(void* const* d_in, const int* in_sizes, int n_in,
                              void* d_out, int out_size, void* d_ws, size_t ws_size,
                              hipStream_t stream) {
  const float* x_n = (const float*)d_in[0];
  const float* x_e = (const float*)d_in[1];
  const int* edge_u = (const int*)d_in[2];
  const int* edge_v = (const int*)d_in[3];
  const int* src_n = (const int*)d_in[4];
  const int* dst_n = (const int*)d_in[5];
  const float* ew_n = (const float*)d_in[6];
  const int* src_e = (const int*)d_in[7];
  const int* dst_e = (const int*)d_in[8];
  const float* ew_e = (const float*)d_in[9];
  const float* W_n = (const float*)d_in[10];
  const float* b_n = (const float*)d_in[11];
  const float* W_e = (const float*)d_in[12];
  const float* b_e = (const float*)d_in[13];
  float* ws = (float*)d_ws;
  float* out = (float*)d_out;

  void* args[] = {
    (void*)&x_n, (void*)&x_e, (void*)&W_n, (void*)&W_e,
    (void*)&src_n, (void*)&dst_n, (void*)&ew_n,
    (void*)&src_e, (void*)&dst_e, (void*)&ew_e,
    (void*)&edge_u, (void*)&edge_v, (void*)&b_n, (void*)&b_e,
    (void*)&ws, (void*)&out
  };
  hipLaunchCooperativeKernel((const void*)k_fused, dim3(NBLK), dim3(NTHR),
                             args, 0, stream);
}

// Round 2
// 459.790 us; speedup vs baseline: 1.2086x; 1.2086x over previous
//
#include <hip/hip_runtime.h>
#include <math.h>

// Problem constants
#define GG 16
#define NNODE 512
#define EEDGE 2048
#define KEEPN 256
#define PITERS 64
#define NNT 8192    // G*N
#define NET 32768   // G*E

typedef float vfloat4 __attribute__((ext_vector_type(4)));

// workspace float offsets
#define WS_C1N 0
#define WS_C2N 8192
#define WS_BN  16384
#define WS_C1E 24576
#define WS_C2E 57344
#define WS_BE  90112
#define WS_SNW 122880   // node score * mask (8192)
#define WS_SEW 131072   // edge score * keep (32768)
#define WS_KLIST 163840 // int[32768]
#define WS_KCNT 196608  // int[16]
#define WS_SCALE 196624 // float[16]

// CSR handoff (int offsets), reusing slices DEAD after their own graph-block
// consumed them inside k_graph:
//   DEG   -> old C1N region  (each block g writes ints [g*512,   g*512+512))
//   START -> old C2N region  (ints [8192+g*512, ...))
//   ADJ   -> old C1E region  (ints [24576+g*2048, ...), 2048 ints = 4096 ushorts)
#define WS_DEG_I   0
#define WS_START_I 8192
#define WS_ADJ_I   24576

// output float offsets: xn | L0 | xe | L1
#define O_XN 0
#define O_L0 524288
#define O_XE 4718592
#define O_L1 6815744

// zero-space: float4 indices over concatenated L0 (1,048,576 f4) || L1
#define L04 1048576      // float4 count of L0
#define ZTOT4 17825792   // total float4 to zero (272 MiB)
#define ZB_LO 6291456    // k_graph zero range [ZB_LO, ZC_LO)
#define ZC_LO 12582912   // k_power zero range [ZC_LO, ZTOT4)

#define DCAP 12

// ---------------------------------------------------------------------------
// K1: channel dots (blocks 0..1023) + zero chunk A (blocks 1024..2047, 96 MiB)
__global__ __launch_bounds__(512) void k_front(
    const float* __restrict__ xn, const float* __restrict__ xe,
    const float* __restrict__ Wn, const float* __restrict__ We,
    float* __restrict__ ws, float* __restrict__ out) {
  const int tid = threadIdx.x, bid = blockIdx.x;
  if (bid >= 1024) {
    vfloat4 z = (vfloat4)(0.f);
    vfloat4* o4 = (vfloat4*)out;
    int base = (bid - 1024) * 512 + tid;
    #pragma unroll
    for (int n = 0; n < 12; ++n) {        // 1024 x 512 x 12 = [0, ZB_LO) exact
      int i = base + n * 524288;
      int f = (i < L04) ? (O_L0 / 4 + i) : (O_L1 / 4 + (i - L04));
      __builtin_nontemporal_store(z, &o4[f]);
    }
    return;
  }
  const int lane = tid & 63;
  const int wv = (bid * 512 + tid) >> 6;   // 0..8191
  #pragma unroll
  for (int n = 0; n < 5; ++n) {
    int gw = wv + n * 8192;                // 0..40959
    const float* x; const float* W; int row; float *c1, *c2, *bs;
    if (gw < NNT) {
      row = gw; x = xn + (size_t)row * 64; W = Wn;
      c1 = ws + WS_C1N; c2 = ws + WS_C2N; bs = ws + WS_BN;
    } else {
      row = gw - NNT;
      x = xe + (size_t)row * 64; W = We;
      c1 = ws + WS_C1E; c2 = ws + WS_C2E; bs = ws + WS_BE;
    }
    float v = x[lane];
    float r0 = v * W[lane];
    float r1 = v * W[64 + lane];
    float r2 = v * W[128 + lane];
    for (int o = 32; o; o >>= 1) {
      r0 += __shfl_xor(r0, o, 64);
      r1 += __shfl_xor(r1, o, 64);
      r2 += __shfl_xor(r2, o, 64);
    }
    if (lane == 0) { c1[row] = r1; c2[row] = r2; bs[row] = r0 + r1 + r2; }
  }
}

// ---------------------------------------------------------------------------
// K2: per-graph MP + scores + top-256 + CSR build (blocks 0..15), CSR exported
// to ws.  Blocks 16..1039 zero chunk B (96 MiB of L1).
#define SM_AUG 0        // 512 f
#define SM_SNW 512      // 512 f, later reused as offS (int)
#define SM_RED 1024     // 8 f
#define SM_IWS 1032     // 8 int
#define SM_KCP 1040     // 1 int
#define SM_S0  1056     // 8200-float scratch
#define SM_TOT 9256
__global__ __launch_bounds__(512) void k_graph(
    const int* __restrict__ src_n, const int* __restrict__ dst_n, const float* __restrict__ wn,
    const int* __restrict__ src_e, const int* __restrict__ dst_e, const float* __restrict__ we,
    const int* __restrict__ edge_u, const int* __restrict__ edge_v,
    const float* __restrict__ bnp, const float* __restrict__ bep,
    float* __restrict__ ws, float* __restrict__ out) {
  const int tid = threadIdx.x;
  if (blockIdx.x >= 16) {
    vfloat4 z = (vfloat4)(0.f);
    vfloat4* o4 = (vfloat4*)out;
    int base = ZB_LO + (blockIdx.x - 16) * 512 + tid;
    #pragma unroll
    for (int n = 0; n < 12; ++n) {        // 1024 x 512 x 12 = [ZB_LO, ZC_LO) exact
      int i = base + n * 524288;
      __builtin_nontemporal_store(z, &o4[O_L1 / 4 + (i - L04)]);
    }
    return;
  }
  __shared__ float smem[SM_TOT];
  int* smi = (int*)smem;
  float* aug = smem + SM_AUG;
  float* snw = smem + SM_SNW;
  int*   iws = smi + SM_IWS;
  int*   kcp = smi + SM_KCP;

  const int g = blockIdx.x;
  const int roffN = g * NNODE;
  const int roffE = g * EEDGE;
  const int lane = tid & 63, wid = tid >> 6;
  float biasN = bnp[0], biasE = bep[0];

  // ---- node message passing (scratch: 5 x 512 at S0) ----
  {
    float* c1n = smem + SM_S0;
    float* c2n = smem + SM_S0 + 512;
    float* d1n = smem + SM_S0 + 1024;
    float* d2n = smem + SM_S0 + 1536;
    float* e2n = smem + SM_S0 + 2048;
    c1n[tid] = ws[WS_C1N + roffN + tid];
    c2n[tid] = ws[WS_C2N + roffN + tid];
    d1n[tid] = 0.f; d2n[tid] = 0.f; e2n[tid] = 0.f;
    __syncthreads();
    for (int t = tid; t < 4096; t += 512) {
      int idx = (t < 2048) ? (g * 2048 + t) : (32768 + g * 2048 + (t - 2048));
      int s = src_n[idx] - roffN, d = dst_n[idx] - roffN;
      float w = wn[idx];
      atomicAdd(&d1n[d], w * c1n[s]);
      atomicAdd(&d2n[d], w * c2n[s]);
    }
    __syncthreads();
    for (int t = tid; t < 4096; t += 512) {
      int idx = (t < 2048) ? (g * 2048 + t) : (32768 + g * 2048 + (t - 2048));
      int s = src_n[idx] - roffN, d = dst_n[idx] - roffN;
      atomicAdd(&e2n[d], wn[idx] * d2n[s]);
    }
    __syncthreads();
    float t = ws[WS_BN + roffN + tid] - d1n[tid] - 2.0f * d2n[tid]
            + 0.5f * e2n[tid] + biasN;
    float s = 1.0f / (1.0f + expf(-t));
    snw[tid] = s; aug[tid] = s;
    __syncthreads();
  }

  // ---- edge message passing ----
  float* seS = smem + SM_S0 + 2048;   // survives into pool phase (old c2e)
  int*   suv = smi + SM_S0;           // packed u|v<<16 (old c1e/e2e, written last)
  {
    float* c1e = smem + SM_S0;
    float* c2e = smem + SM_S0 + 2048;
    float* d1e = smem + SM_S0 + 4096;
    float* d2e = smem + SM_S0 + 6144;
    float* e2e = smem + SM_S0;        // aliases c1e after hop 1
    for (int i = tid; i < EEDGE; i += 512) {
      c1e[i] = ws[WS_C1E + roffE + i];
      c2e[i] = ws[WS_C2E + roffE + i];
      d1e[i] = 0.f; d2e[i] = 0.f;
    }
    __syncthreads();
    for (int t = tid; t < 8192; t += 512) {
      int idx = g * 8192 + t;
      int s = src_e[idx] - roffE, d = dst_e[idx] - roffE;
      float w = we[idx];
      atomicAdd(&d1e[d], w * c1e[s]);
      atomicAdd(&d2e[d], w * c2e[s]);
    }
    __syncthreads();
    for (int i = tid; i < EEDGE; i += 512) e2e[i] = 0.f;
    __syncthreads();
    for (int t = tid; t < 8192; t += 512) {
      int idx = g * 8192 + t;
      int s = src_e[idx] - roffE, d = dst_e[idx] - roffE;
      atomicAdd(&e2e[d], we[idx] * d2e[s]);
    }
    __syncthreads();
    for (int e = tid; e < EEDGE; e += 512) {
      float t = ws[WS_BE + roffE + e] - d1e[e] - 2.0f * d2e[e]
              + 0.5f * e2e[e] + biasE;
      float s = 1.0f / (1.0f + expf(-t));
      int u = edge_u[roffE + e], v = edge_v[roffE + e];
      seS[e] = s;                       // seS == c2e slot e (c2 dead)
      suv[e] = u | (v << 16);           // suv == e2e slot e (read before write)
      atomicAdd(&aug[u], s);
      atomicAdd(&aug[v], s);
    }
    __syncthreads();
  }

  // ---- pool-phase scratch ----
  unsigned short* adjU = (unsigned short*)(smem + SM_S0 + 4096); // 4096 ushorts
  int* maskS = smi + SM_S0 + 7176;
  int* degS  = smi + SM_S0 + 7688;
  int* offS  = smi + SM_SNW;          // reuses snw after SNW written out

  // ---- rank-based top-256 (exact stable argsort(-aug)[:256]) ----
  {
    float a = aug[tid];
    int r = 0;
    #pragma unroll 8
    for (int j = 0; j < NNODE; ++j) {
      float b = aug[j];
      r += (b > a) || (b == a && j < tid);
    }
    maskS[tid] = (r < KEEPN) ? 1 : 0;
    degS[tid] = 0;
  }
  if (tid == 0) *kcp = 0;
  __syncthreads();
  ws[WS_SNW + roffN + tid] = snw[tid] * (float)maskS[tid];

  // ---- keep_e, klist compaction, degree count ----
  int* wsi = (int*)ws;
  for (int e = tid; e < EEDGE; e += 512) {
    int p2 = suv[e];
    int u = p2 & 0xffff, v = p2 >> 16;
    int k = maskS[u] & maskS[v];
    ws[WS_SEW + roffE + e] = seS[e] * (float)k;
    if (k) {
      int p = atomicAdd(kcp, 1);
      wsi[WS_KLIST + roffE + p] = e;
      atomicAdd(&degS[u], 1);
      atomicAdd(&degS[v], 1);
    }
  }
  __syncthreads();
  if (tid == 0) wsi[WS_KCNT + g] = *kcp;

  // ---- exclusive prefix of deg via wave scan ----
  int dv = degS[tid];
  int inc = dv;
  for (int o = 1; o < 64; o <<= 1) {
    int t = __shfl_up(inc, o, 64);
    if (lane >= o) inc += t;
  }
  if (lane == 63) iws[wid] = inc;
  __syncthreads();
  int base = 0;
  for (int k = 0; k < wid; ++k) base += iws[k];
  int myStart = base + inc - dv;
  offS[tid] = myStart;
  __syncthreads();

  // ---- CSR fill (ushort adjacency) ----
  for (int e = tid; e < EEDGE; e += 512) {
    int p2 = suv[e];
    int u = p2 & 0xffff, v = p2 >> 16;
    if (maskS[u] & maskS[v]) {
      int pu = atomicAdd(&offS[u], 1); adjU[pu] = (unsigned short)v;
      int pv = atomicAdd(&offS[v], 1); adjU[pv] = (unsigned short)u;
    }
  }
  __syncthreads();

  // ---- export CSR to ws (own-graph dead slices only) ----
  wsi[WS_DEG_I + roffN + tid] = dv;
  wsi[WS_START_I + roffN + tid] = myStart;
  {
    int* adjI = (int*)adjU;
    for (int i = tid; i < 2048; i += 512)
      wsi[WS_ADJ_I + roffE + i] = adjI[i];
  }
}

// ---------------------------------------------------------------------------
// K3: power iteration + Rayleigh (blocks 0..15); blocks 16..1039 zero chunk C.
#define PSM_ADJ 0        // 2048 ints (4096 ushorts)
#define PSM_WVA 2048     // 516 f
#define PSM_WVB 2564     // 516 f
#define PSM_RED 3080     // 8 f
#define PSM_TOT 3088
__global__ __launch_bounds__(512) void k_power(
    float* __restrict__ ws, float* __restrict__ out) {
  const int tid = threadIdx.x;
  if (blockIdx.x >= 16) {
    vfloat4 z = (vfloat4)(0.f);
    vfloat4* o4 = (vfloat4*)out;
    int base = ZC_LO + (blockIdx.x - 16) * 512 + tid;
    #pragma unroll
    for (int n = 0; n < 10; ++n) {        // 1024 x 512 x 10 = [ZC_LO, ZTOT4) exact
      int i = base + n * 524288;
      __builtin_nontemporal_store(z, &o4[O_L1 / 4 + (i - L04)]);
    }
    return;
  }
  __shared__ float smem[PSM_TOT];
  int* smi = (int*)smem;
  unsigned short* adjU = (unsigned short*)(smi + PSM_ADJ);
  float* wvA = smem + PSM_WVA;
  float* wvB = smem + PSM_WVB;
  float* red = smem + PSM_RED;

  const int g = blockIdx.x;
  const int lane = tid & 63, wid = tid >> 6;
  const int* wsi = (const int*)ws;

  for (int i = tid; i < 2048; i += 512)
    smi[PSM_ADJ + i] = wsi[WS_ADJ_I + g * EEDGE + i];
  int myDeg = wsi[WS_DEG_I + g * NNODE + tid];
  int myStart = wsi[WS_START_I + g * NNODE + tid];
  int myEnd = myStart + myDeg;
  __syncthreads();

  // ---- register-cached adjacency (pad -> pinned zero cell 512) ----
  int nbr[DCAP];
  #pragma unroll
  for (int k = 0; k < DCAP; ++k)
    nbr[k] = (k < myDeg) ? (int)adjU[myStart + k] : NNODE;
  bool ovf = myDeg > DCAP;

  wvA[tid] = 0.04419417382415922f; // 1/sqrt(512)
  if (tid == 0) { wvA[NNODE] = 0.f; wvB[NNODE] = 0.f; }
  __syncthreads();
  float* wcur = wvA; float* wnext = wvB;
  for (int it = 0; it < PITERS; ++it) {
    float acc = (float)myDeg * wcur[tid];
    #pragma unroll
    for (int k = 0; k < DCAP; ++k) acc -= wcur[nbr[k]];
    if (ovf) for (int p = myStart + DCAP; p < myEnd; ++p) acc -= wcur[(int)adjU[p]];
    if ((it & 7) == 7) {
      float sq = acc * acc;
      for (int o = 32; o; o >>= 1) sq += __shfl_xor(sq, o, 64);
      if (lane == 0) red[wid] = sq;
      __syncthreads();
      float tot = red[0] + red[1] + red[2] + red[3]
                + red[4] + red[5] + red[6] + red[7];
      wnext[tid] = acc * (1.0f / (sqrtf(tot) + 1e-12f));
    } else {
      wnext[tid] = acc;
    }
    __syncthreads();
    float* tmp = wcur; wcur = wnext; wnext = tmp;
  }
  // ---- Rayleigh quotient (iter 63 normalized) ----
  {
    float wv_ = wcur[tid];
    float acc = (float)myDeg * wv_;
    #pragma unroll
    for (int k = 0; k < DCAP; ++k) acc -= wcur[nbr[k]];
    if (ovf) for (int p = myStart + DCAP; p < myEnd; ++p) acc -= wcur[(int)adjU[p]];
    float pr = wv_ * acc;
    for (int o = 32; o; o >>= 1) pr += __shfl_xor(pr, o, 64);
    if (lane == 0) red[wid] = pr;
    __syncthreads();
    if (tid == 0) {
      float lam = red[0] + red[1] + red[2] + red[3]
                + red[4] + red[5] + red[6] + red[7];
      ws[WS_SCALE + g] = 2.0f / (lam + 1e-12f);
    }
  }
}

// ---------------------------------------------------------------------------
// K4: outputs. [0,512) xn dense; [512,2560) xe dense; [2560,2576) L0 scatter;
// [2576,6672) L1 pair enumeration over compacted kept edges.
__global__ __launch_bounds__(256) void k_out(
    const float* __restrict__ xn, const float* __restrict__ xe,
    const int* __restrict__ edge_u, const int* __restrict__ edge_v,
    const float* __restrict__ ws, float* __restrict__ out) {
  int b = blockIdx.x, tid = threadIdx.x;
  const int* wsi = (const int*)ws;
  if (b < 512) {
    int idx = b * 256 + tid;
    int row = idx >> 4;
    float s = ws[WS_SNW + row];
    float4 x4 = ((const float4*)xn)[idx];
    ((float4*)(out + O_XN))[idx] = make_float4(x4.x * s, x4.y * s, x4.z * s, x4.w * s);
  } else if (b < 2560) {
    int idx = (b - 512) * 256 + tid;
    int row = idx >> 4;
    float s = ws[WS_SEW + row];
    float4 x4 = ((const float4*)xe)[idx];
    ((float4*)(out + O_XE))[idx] = make_float4(x4.x * s, x4.y * s, x4.z * s, x4.w * s);
  } else if (b < 2576) {
    int g = b - 2560;
    int cnt = wsi[WS_KCNT + g];
    float s = ws[WS_SCALE + g];
    float* L0 = out + O_L0 + (long long)g * (NNODE * NNODE);
    const int* kl = wsi + WS_KLIST + g * EEDGE;
    const int* eu = edge_u + g * EEDGE;
    const int* ev = edge_v + g * EEDGE;
    for (int t = tid; t < cnt; t += 256) {
      int e = kl[t];
      int u = eu[e], v = ev[e];
      atomicAdd(&L0[u * NNODE + u], s);
      atomicAdd(&L0[v * NNODE + v], s);
      atomicAdd(&L0[u * NNODE + v], -s);
      atomicAdd(&L0[v * NNODE + u], -s);
    }
  } else {
    int q = b - 2576;
    int g = q >> 8, sb = q & 255;
    int cnt = wsi[WS_KCNT + g];
    float s = ws[WS_SCALE + g];
    float* L1 = out + O_L1 + (long long)g * (EEDGE * EEDGE);
    const int* kl = wsi + WS_KLIST + g * EEDGE;
    const int* eu = edge_u + g * EEDGE;
    const int* ev = edge_v + g * EEDGE;
    for (int a = sb; a < cnt; a += 256) {
      int e1 = kl[a];
      int u1 = eu[e1], v1 = ev[e1];
      long long rowoff = (long long)e1 * EEDGE;
      for (int b2 = tid; b2 < cnt; b2 += 256) {
        int e2 = kl[b2];
        int u2 = eu[e2], v2 = ev[e2];
        int val = (u1 == u2) + (v1 == v2) - (v1 == u2) - (u1 == v2);
        if (val) L1[rowoff + e2] = s * (float)val;
      }
    }
  }
}

// ---------------------------------------------------------------------------
extern "C" void kernel_launch(void* const* d_in, const int* in_sizes, int n_in,
                              void* d_out, int out_size, void* d_ws, size_t ws_size,
                              hipStream_t stream) {
  const float* x_n = (const float*)d_in[0];
  const float* x_e = (const float*)d_in[1];
  const int* edge_u = (const int*)d_in[2];
  const int* edge_v = (const int*)d_in[3];
  const int* src_n = (const int*)d_in[4];
  const int* dst_n = (const int*)d_in[5];
  const float* ew_n = (const float*)d_in[6];
  const int* src_e = (const int*)d_in[7];
  const int* dst_e = (const int*)d_in[8];
  const float* ew_e = (const float*)d_in[9];
  const float* W_n = (const float*)d_in[10];
  const float* b_n = (const float*)d_in[11];
  const float* W_e = (const float*)d_in[12];
  const float* b_e = (const float*)d_in[13];
  float* ws = (float*)d_ws;
  float* out = (float*)d_out;

  // K1: channel dots (1024 blocks) + zero chunk A (1024 blocks, 96 MiB)
  k_front<<<2048, 512, 0, stream>>>(x_n, x_e, W_n, W_e, ws, out);
  // K2: MP + scores + top-256 + CSR (16) + zero chunk B (1024 blocks, 96 MiB)
  k_graph<<<16 + 1024, 512, 0, stream>>>(src_n, dst_n, ew_n, src_e, dst_e, ew_e,
                                         edge_u, edge_v, b_n, b_e, ws, out);
  // K3: power iteration (16) + zero chunk C (1024 blocks, 80 MiB)
  k_power<<<16 + 1024, 512, 0, stream>>>(ws, out);
  // K4: dense xn/xe + sparse L0/L1 scatter
  k_out<<<6672, 256, 0, stream>>>(x_n, x_e, edge_u, edge_v, ws, out);
}